// Round 4
// baseline (864.919 us; speedup 1.0000x reference)
//
#include <hip/hip_runtime.h>
#include <stdint.h>

#define NB 1024
#define ND 512
#define NC 100000
#define MT 782           // ceil(NC/128)
#define MARGINF 0.1f

using bf16x8 = __attribute__((ext_vector_type(8))) short;
using f32x4  = __attribute__((ext_vector_type(4))) float;

// ---------- helpers ----------
__device__ __forceinline__ uint32_t f2bf(float f) {
  // round-to-nearest-even fp32 -> bf16
  uint32_t u = __float_as_uint(f);
  return (u + 0x7fffu + ((u >> 16) & 1u)) >> 16;
}
__device__ __forceinline__ uint32_t pack2bf(float x, float y) {
  return f2bf(x) | (f2bf(y) << 16);
}

// ---------- kernel 1: normalize inputs fp32 -> bf16, one wave per row ----------
__global__ __launch_bounds__(256)
void normalize_x_kernel(const float* __restrict__ src,
                        uint16_t* __restrict__ dst, int nrows) {
  const int lane = threadIdx.x & 63;
  const int wid = (blockIdx.x << 2) + (threadIdx.x >> 6);
  if (wid >= nrows) return;
  const float4* s = (const float4*)(src + (size_t)wid * ND) + (lane << 1);
  float4 a = s[0], b = s[1];
  float ss = a.x*a.x + a.y*a.y + a.z*a.z + a.w*a.w
           + b.x*b.x + b.y*b.y + b.z*b.z + b.w*b.w;
  #pragma unroll
  for (int o = 32; o; o >>= 1) ss += __shfl_xor(ss, o);
  const float inv = 1.0f / fmaxf(sqrtf(ss), 1e-8f);
  uint4 o4;
  o4.x = pack2bf(a.x * inv, a.y * inv);
  o4.y = pack2bf(a.z * inv, a.w * inv);
  o4.z = pack2bf(b.x * inv, b.y * inv);
  o4.w = pack2bf(b.z * inv, b.w * inv);
  ((uint4*)(dst + (size_t)wid * ND))[lane] = o4;
}

// ---------- kernel 2: exact fp32 target cosine t_b ----------
__global__ void target_cos_kernel(const float* __restrict__ x,
                                  const float* __restrict__ cls,
                                  const int* __restrict__ tgt,
                                  float* __restrict__ t) {
  const int b = blockIdx.x;
  const int row = tgt[b];
  const float2* xr = (const float2*)(x + (size_t)b * ND);
  const float2* cr = (const float2*)(cls + (size_t)row * ND);
  float2 xv = xr[threadIdx.x], cv = cr[threadIdx.x];
  float sx = xv.x * xv.x + xv.y * xv.y;
  float sc = cv.x * cv.x + cv.y * cv.y;
  float sd = xv.x * cv.x + xv.y * cv.y;
  #pragma unroll
  for (int o = 32; o; o >>= 1) {
    sx += __shfl_down(sx, o);
    sc += __shfl_down(sc, o);
    sd += __shfl_down(sd, o);
  }
  __shared__ float r[3][4];
  const int wv = threadIdx.x >> 6;
  if ((threadIdx.x & 63) == 0) { r[0][wv] = sx; r[1][wv] = sc; r[2][wv] = sd; }
  __syncthreads();
  if (threadIdx.x == 0) {
    float ax = r[0][0] + r[0][1] + r[0][2] + r[0][3];
    float ac = r[1][0] + r[1][1] + r[1][2] + r[1][3];
    float ad = r[2][0] + r[2][1] + r[2][2] + r[2][3];
    t[b] = ad / (fmaxf(sqrtf(ax), 1e-8f) * fmaxf(sqrtf(ac), 1e-8f));
  }
}

// ---------- kernel 3: FUSED normalize-classes + MFMA GEMM + hinge reduction ----
// 256 threads = 4 waves (wm = wv&1, wn = wv>>1). Tile M=128 classes x N=128
// inputs, BK=64, wave computes 64x64 via 4x4 of 16x16x32 MFMAs.
// A (classes) is read RAW fp32, converted to bf16 in VGPRs, ds_write'd into
// fragment-order LDS; per-row sumsq accumulated on the fly, scores scaled by
// rsqrt in the epilogue (cosine vs bf16-rounded class vector — within tol).
// B (normalized inputs, bf16) staged via global_load_lds.
// LDS fragment region r: 1KB, lane L at r*1024 + L*16.
//   A regions 0..15 : r = s*2 + ki (s = m-subtile 0..7)
//   B regions 0..15 : r = s*2 + ki (s = n-subtile 0..7)
__global__ __launch_bounds__(256)
void hinge_gemm_fused(const float* __restrict__ Wraw,    // [NC][ND] fp32 raw
                      const uint16_t* __restrict__ Xn,   // [NB][ND] bf16 normalized
                      const float* __restrict__ t,       // [NB]
                      float* __restrict__ accum) {
  __shared__ __align__(16) uint16_t ldsA[8192];   // 16 KB
  __shared__ __align__(16) uint16_t ldsB[8192];   // 16 KB
  __shared__ float norms[128];
  __shared__ float part[4];
  const int id = blockIdx.x;
  // XCD swizzle: the 8 n-tiles of one m-tile share id%8 -> same XCD L2 reuse of Wraw
  const int nt = (id >> 3) & 7;
  const int mt = (id & 7) + ((id >> 6) << 3);
  if (mt >= MT) return;
  const int m0 = mt << 7, n0 = nt << 7;
  const int lane = threadIdx.x & 63;
  const int wv = threadIdx.x >> 6;       // 0..3
  const int wm = wv & 1, wn = wv >> 1;
  const int lr = lane & 15;
  const int lg = lane >> 4;              // 0..3
  const int s0 = wv << 1;                // this wave stages subtiles s0, s0+1

  int rowA0 = m0 + (s0 << 4) + lr;       if (rowA0 > NC - 1) rowA0 = NC - 1;
  int rowA1 = m0 + ((s0 + 1) << 4) + lr; if (rowA1 > NC - 1) rowA1 = NC - 1;
  const float* pA0 = Wraw + (size_t)rowA0 * ND + (lg << 3);
  const float* pA1 = Wraw + (size_t)rowA1 * ND + (lg << 3);
  const uint16_t* pB0 = Xn + (size_t)(n0 + (s0 << 4) + lr) * ND + (lg << 3);
  const uint16_t* pB1 = Xn + (size_t)(n0 + ((s0 + 1) << 4) + lr) * ND + (lg << 3);

  f32x4 acc[4][4];
  #pragma unroll
  for (int i = 0; i < 4; ++i)
    #pragma unroll
    for (int j = 0; j < 4; ++j)
      acc[i][j] = (f32x4){0.f, 0.f, 0.f, 0.f};

  float ssq0 = 0.f, ssq1 = 0.f;

  #pragma unroll
  for (int kk = 0; kk < 8; ++kk) {
    const int kb = kk << 6;              // k offset in elements
    // ---- B: async DMA, 4 regions (s0,s0+1) x (ki 0,1) ----
    #pragma unroll
    for (int ki = 0; ki < 2; ++ki) {
      __builtin_amdgcn_global_load_lds(
          (const __attribute__((address_space(1))) void*)(pB0 + kb + (ki << 5)),
          (__attribute__((address_space(3))) void*)(ldsB + (((s0 << 1) + ki) << 9)),
          16, 0, 0);
      __builtin_amdgcn_global_load_lds(
          (const __attribute__((address_space(1))) void*)(pB1 + kb + (ki << 5)),
          (__attribute__((address_space(3))) void*)(ldsB + ((((s0 + 1) << 1) + ki) << 9)),
          16, 0, 0);
    }
    // ---- A: fp32 loads -> cvt bf16 -> ds_write (pipelinable across iters) ----
    #pragma unroll
    for (int ki = 0; ki < 2; ++ki) {
      const float4* a0 = (const float4*)(pA0 + kb + (ki << 5));
      const float4* a1 = (const float4*)(pA1 + kb + (ki << 5));
      float4 v0 = a0[0], v1 = a0[1];
      float4 w0 = a1[0], w1 = a1[1];
      ssq0 += v0.x*v0.x + v0.y*v0.y + v0.z*v0.z + v0.w*v0.w
            + v1.x*v1.x + v1.y*v1.y + v1.z*v1.z + v1.w*v1.w;
      ssq1 += w0.x*w0.x + w0.y*w0.y + w0.z*w0.z + w0.w*w0.w
            + w1.x*w1.x + w1.y*w1.y + w1.z*w1.z + w1.w*w1.w;
      uint4 u0, u1;
      u0.x = pack2bf(v0.x, v0.y); u0.y = pack2bf(v0.z, v0.w);
      u0.z = pack2bf(v1.x, v1.y); u0.w = pack2bf(v1.z, v1.w);
      u1.x = pack2bf(w0.x, w0.y); u1.y = pack2bf(w0.z, w0.w);
      u1.z = pack2bf(w1.x, w1.y); u1.w = pack2bf(w1.z, w1.w);
      *(uint4*)(ldsA + (((s0 << 1) + ki) << 9) + (lane << 3)) = u0;
      *(uint4*)(ldsA + ((((s0 + 1) << 1) + ki) << 9) + (lane << 3)) = u1;
    }
    __syncthreads();
    // ---- compute: 2 k-slices x 4x4 MFMAs ----
    #pragma unroll
    for (int ki = 0; ki < 2; ++ki) {
      bf16x8 af[4], bfr[4];
      #pragma unroll
      for (int ms = 0; ms < 4; ++ms)
        af[ms] = *(const bf16x8*)((const char*)ldsA +
                 ((((wm << 2) + ms) * 2 + ki) << 10) + (lane << 4));
      #pragma unroll
      for (int j = 0; j < 4; ++j)
        bfr[j] = *(const bf16x8*)((const char*)ldsB +
                 ((((wn << 2) + j) * 2 + ki) << 10) + (lane << 4));
      #pragma unroll
      for (int ms = 0; ms < 4; ++ms)
        #pragma unroll
        for (int j = 0; j < 4; ++j)
          acc[ms][j] = __builtin_amdgcn_mfma_f32_16x16x32_bf16(af[ms], bfr[j], acc[ms][j], 0, 0, 0);
    }
    __syncthreads();
  }

  // ---- per-class inverse norms (of the raw fp32 rows) ----
  ssq0 += __shfl_xor(ssq0, 16); ssq0 += __shfl_xor(ssq0, 32);
  ssq1 += __shfl_xor(ssq1, 16); ssq1 += __shfl_xor(ssq1, 32);
  if (lane < 16) {
    norms[(s0 << 4) + lr]       = 1.0f / fmaxf(sqrtf(ssq0), 1e-8f);
    norms[((s0 + 1) << 4) + lr] = 1.0f / fmaxf(sqrtf(ssq1), 1e-8f);
  }
  __syncthreads();

  // ---- epilogue: scale + hinge + block reduction ----
  // C/D layout: col(N) = lane&15, row(M) = (lane>>4)*4 + reg
  float local = 0.f;
  #pragma unroll
  for (int j = 0; j < 4; ++j) {
    const int n = n0 + ((wn << 2) + j) * 16 + lr;
    const float base = MARGINF - t[n];
    #pragma unroll
    for (int ms = 0; ms < 4; ++ms) {
      const int mloc = ((wm << 2) + ms) * 16 + (lg << 2);
      f32x4 v = acc[ms][j];
      #pragma unroll
      for (int rr = 0; rr < 4; ++rr)
        if (m0 + mloc + rr < NC)
          local += fmaxf(base + v[rr] * norms[mloc + rr], 0.f);
    }
  }
  #pragma unroll
  for (int o = 32; o; o >>= 1) local += __shfl_down(local, o);
  if (lane == 0) part[wv] = local;
  __syncthreads();
  if (threadIdx.x == 0)
    atomicAdd(accum, part[0] + part[1] + part[2] + part[3]);
}

// ---------- kernel 4: finalize ----------
__global__ void finalize_kernel(const float* __restrict__ accum, float* __restrict__ out) {
  out[0] = accum[0] * (1.0f / (float)NB) - MARGINF;
}

// ---------- workspace layout ----------
//   Xn   : 0         .. 1,048,576    (NB*ND bf16)
//   t    : 1,048,576 .. 1,052,672    (NB fp32)
//   acc  : 1,052,672 .. +4
#define WS_XN 0
#define WS_T  1048576ull
#define WS_ACC 1052672ull

extern "C" void kernel_launch(void* const* d_in, const int* in_sizes, int n_in,
                              void* d_out, int out_size, void* d_ws, size_t ws_size,
                              hipStream_t stream) {
  const float* inputs = (const float*)d_in[0];
  const float* cls    = (const float*)d_in[1];
  const int*   tgt    = (const int*)d_in[2];
  float* out = (float*)d_out;
  char* ws = (char*)d_ws;
  uint16_t* Xn = (uint16_t*)(ws + WS_XN);
  float* t     = (float*)(ws + WS_T);
  float* accum = (float*)(ws + WS_ACC);

  (void)hipMemsetAsync(accum, 0, sizeof(float), stream);
  normalize_x_kernel<<<256, 256, 0, stream>>>(inputs, Xn, NB);
  target_cos_kernel<<<NB, 256, 0, stream>>>(inputs, cls, tgt, t);
  // grid: 98 * 64 = 6272 (782 m-tiles x 8 n-tiles, XCD-swizzled)
  hinge_gemm_fused<<<6272, 256, 0, stream>>>(cls, Xn, t, accum);
  finalize_kernel<<<1, 1, 0, stream>>>(accum, out);
}

// Round 5
// 689.288 us; speedup vs baseline: 1.2548x; 1.2548x over previous
//
#include <hip/hip_runtime.h>
#include <stdint.h>

#define NB 1024
#define ND 512
#define NC 100000
#define MT 782           // ceil(NC/128)
#define MARGINF 0.1f

using bf16x8 = __attribute__((ext_vector_type(8))) short;
using f32x4  = __attribute__((ext_vector_type(4))) float;

// ---------- helpers ----------
__device__ __forceinline__ uint32_t f2bf(float f) {
  // round-to-nearest-even fp32 -> bf16
  uint32_t u = __float_as_uint(f);
  return (u + 0x7fffu + ((u >> 16) & 1u)) >> 16;
}
__device__ __forceinline__ uint32_t pack2bf(float x, float y) {
  return f2bf(x) | (f2bf(y) << 16);
}

// ---------- kernel 1: row-normalize fp32 -> bf16, one wave per row ----------
__global__ __launch_bounds__(256)
void normalize_rows_kernel(const float* __restrict__ src,
                           uint16_t* __restrict__ dst, int nrows) {
  const int lane = threadIdx.x & 63;
  const int wid = (blockIdx.x << 2) + (threadIdx.x >> 6);
  const int nw = gridDim.x << 2;
  for (int row = wid; row < nrows; row += nw) {
    const float4* s = (const float4*)(src + (size_t)row * ND) + (lane << 1);
    float4 a = s[0], b = s[1];
    float ss = a.x*a.x + a.y*a.y + a.z*a.z + a.w*a.w
             + b.x*b.x + b.y*b.y + b.z*b.z + b.w*b.w;
    #pragma unroll
    for (int o = 32; o; o >>= 1) ss += __shfl_xor(ss, o);
    const float inv = 1.0f / fmaxf(sqrtf(ss), 1e-8f);
    uint4 o4;
    o4.x = pack2bf(a.x * inv, a.y * inv);
    o4.y = pack2bf(a.z * inv, a.w * inv);
    o4.z = pack2bf(b.x * inv, b.y * inv);
    o4.w = pack2bf(b.z * inv, b.w * inv);
    ((uint4*)(dst + (size_t)row * ND))[lane] = o4;
  }
}

// ---------- kernel 2: exact fp32 target cosine t_b ----------
__global__ void target_cos_kernel(const float* __restrict__ x,
                                  const float* __restrict__ cls,
                                  const int* __restrict__ tgt,
                                  float* __restrict__ t) {
  const int b = blockIdx.x;
  const int row = tgt[b];
  const float2* xr = (const float2*)(x + (size_t)b * ND);
  const float2* cr = (const float2*)(cls + (size_t)row * ND);
  float2 xv = xr[threadIdx.x], cv = cr[threadIdx.x];
  float sx = xv.x * xv.x + xv.y * xv.y;
  float sc = cv.x * cv.x + cv.y * cv.y;
  float sd = xv.x * cv.x + xv.y * cv.y;
  #pragma unroll
  for (int o = 32; o; o >>= 1) {
    sx += __shfl_down(sx, o);
    sc += __shfl_down(sc, o);
    sd += __shfl_down(sd, o);
  }
  __shared__ float r[3][4];
  const int wv = threadIdx.x >> 6;
  if ((threadIdx.x & 63) == 0) { r[0][wv] = sx; r[1][wv] = sc; r[2][wv] = sd; }
  __syncthreads();
  if (threadIdx.x == 0) {
    float ax = r[0][0] + r[0][1] + r[0][2] + r[0][3];
    float ac = r[1][0] + r[1][1] + r[1][2] + r[1][3];
    float ad = r[2][0] + r[2][1] + r[2][2] + r[2][3];
    t[b] = ad / (fmaxf(sqrtf(ax), 1e-8f) * fmaxf(sqrtf(ac), 1e-8f));
  }
}

// ---------- kernel 3: NO-LDS direct-register MFMA GEMM + hinge reduction ------
// 256 threads = 4 waves in 2x2 (wm=wv&1, wn=wv>>1). Block tile M=128 x N=128,
// wave tile 64x64 = 4x4 of 16x16x32 MFMAs per BK=32 k-step, 16 k-steps.
// NO __syncthreads in the K-loop: each lane loads its MFMA fragments straight
// from global memory (fragment layout row=lane&15, k-off=(lane>>4)*8 is 16B
// contiguous per lane in a row-major [row][k] matrix). Explicit 2-deep
// software pipeline (depth-3 rotating buffers) lets loads stay in flight
// behind MFMAs — the fine-grained-vmcnt pattern the barriered K-loop forbids.
__global__ __launch_bounds__(256, 2)
void hinge_gemm_direct(const uint16_t* __restrict__ Wn,   // [NC][ND] bf16 norm
                       const uint16_t* __restrict__ Xn,   // [NB][ND] bf16 norm
                       const float* __restrict__ t,       // [NB]
                       float* __restrict__ accum) {
  const int id = blockIdx.x;
  // XCD swizzle: m-tile mt pinned to XCD (mt&7); its 8 n-tiles arrive on
  // consecutive (id>>3) groups -> Wn tile stays hot in that XCD's L2.
  const int nt = (id >> 3) & 7;
  const int mt = (id & 7) + ((id >> 6) << 3);
  if (mt >= MT) return;
  const int m0 = mt << 7, n0 = nt << 7;
  const int lane = threadIdx.x & 63;
  const int wv = threadIdx.x >> 6;       // 0..3
  const int wm = wv & 1, wn = wv >> 1;   // 2x2 wave grid
  const int lr = lane & 15;
  const int koff = (lane >> 4) << 3;     // 0,8,16,24

  // fragment base pointers (bump by 32 elems per k-step)
  const uint16_t* pA[4];
  const uint16_t* pB[4];
  #pragma unroll
  for (int ms = 0; ms < 4; ++ms) {
    int row = m0 + (wm << 6) + (ms << 4) + lr;
    if (row > NC - 1) row = NC - 1;      // clamp; masked in epilogue
    pA[ms] = Wn + (size_t)row * ND + koff;
  }
  #pragma unroll
  for (int j = 0; j < 4; ++j) {
    const int row = n0 + (wn << 6) + (j << 4) + lr;
    pB[j] = Xn + (size_t)row * ND + koff;
  }

  f32x4 acc[4][4];
  #pragma unroll
  for (int i = 0; i < 4; ++i)
    #pragma unroll
    for (int j = 0; j < 4; ++j)
      acc[i][j] = (f32x4){0.f, 0.f, 0.f, 0.f};

  bf16x8 abuf[3][4], bbuf[3][4];
  // prologue: stages 0 and 1 in flight
  #pragma unroll
  for (int s = 0; s < 2; ++s) {
    #pragma unroll
    for (int ms = 0; ms < 4; ++ms) abuf[s][ms] = *(const bf16x8*)(pA[ms] + (s << 5));
    #pragma unroll
    for (int j = 0; j < 4; ++j)    bbuf[s][j]  = *(const bf16x8*)(pB[j] + (s << 5));
  }
  #pragma unroll
  for (int kk = 0; kk < 16; ++kk) {
    const int sl = kk % 3;
    if (kk + 2 < 16) {
      const int sn = (kk + 2) % 3;
      #pragma unroll
      for (int ms = 0; ms < 4; ++ms)
        abuf[sn][ms] = *(const bf16x8*)(pA[ms] + ((kk + 2) << 5));
      #pragma unroll
      for (int j = 0; j < 4; ++j)
        bbuf[sn][j] = *(const bf16x8*)(pB[j] + ((kk + 2) << 5));
    }
    #pragma unroll
    for (int ms = 0; ms < 4; ++ms)
      #pragma unroll
      for (int j = 0; j < 4; ++j)
        acc[ms][j] = __builtin_amdgcn_mfma_f32_16x16x32_bf16(abuf[sl][ms], bbuf[sl][j], acc[ms][j], 0, 0, 0);
  }

  // ---- epilogue: hinge + block reduction ----
  // C/D layout: col(N) = lane&15, row(M) = (lane>>4)*4 + reg
  float local = 0.f;
  const int rb4 = (lane >> 4) << 2;
  #pragma unroll
  for (int j = 0; j < 4; ++j) {
    const int n = n0 + (wn << 6) + (j << 4) + lr;
    const float base = MARGINF - t[n];
    #pragma unroll
    for (int ms = 0; ms < 4; ++ms) {
      const int mr = m0 + (wm << 6) + (ms << 4) + rb4;
      f32x4 v = acc[ms][j];
      #pragma unroll
      for (int rr = 0; rr < 4; ++rr)
        if (mr + rr < NC) local += fmaxf(base + v[rr], 0.f);
    }
  }
  #pragma unroll
  for (int o = 32; o; o >>= 1) local += __shfl_down(local, o);
  __shared__ float part[4];
  if (lane == 0) part[wv] = local;
  __syncthreads();
  if (threadIdx.x == 0)
    atomicAdd(accum, part[0] + part[1] + part[2] + part[3]);
}

// ---------- kernel 4: finalize ----------
__global__ void finalize_kernel(const float* __restrict__ accum, float* __restrict__ out) {
  out[0] = accum[0] * (1.0f / (float)NB) - MARGINF;
}

// ---------- workspace layout ----------
//   Wn   : 0            .. 102,400,000   (NC*ND bf16)
//   Xn   : 102,400,000  .. 103,448,576   (NB*ND bf16)
//   t    : 103,448,576  .. 103,452,672   (NB fp32)
//   acc  : 103,452,672  .. +4
#define WS_WN 0
#define WS_XN 102400000ull
#define WS_T  103448576ull
#define WS_ACC 103452672ull

extern "C" void kernel_launch(void* const* d_in, const int* in_sizes, int n_in,
                              void* d_out, int out_size, void* d_ws, size_t ws_size,
                              hipStream_t stream) {
  const float* inputs = (const float*)d_in[0];
  const float* cls    = (const float*)d_in[1];
  const int*   tgt    = (const int*)d_in[2];
  float* out = (float*)d_out;
  char* ws = (char*)d_ws;
  uint16_t* Wn = (uint16_t*)(ws + WS_WN);
  uint16_t* Xn = (uint16_t*)(ws + WS_XN);
  float* t     = (float*)(ws + WS_T);
  float* accum = (float*)(ws + WS_ACC);

  (void)hipMemsetAsync(accum, 0, sizeof(float), stream);
  normalize_rows_kernel<<<256, 256, 0, stream>>>(inputs, Xn, NB);
  normalize_rows_kernel<<<4096, 256, 0, stream>>>(cls, Wn, NC);
  target_cos_kernel<<<NB, 256, 0, stream>>>(inputs, cls, tgt, t);
  // grid: 98*64 = 6272 covers 782 m-tiles x 8 n-tiles (guarded), XCD-swizzled
  hinge_gemm_direct<<<6272, 256, 0, stream>>>(Wn, Xn, t, accum);
  finalize_kernel<<<1, 1, 0, stream>>>(accum, out);
}

// Round 6
// 447.830 us; speedup vs baseline: 1.9314x; 1.5392x over previous
//
#include <hip/hip_runtime.h>
#include <stdint.h>

#define NB 1024
#define ND 512
#define NC 100000
#define MT 782           // ceil(NC/128)
#define MARGINF 0.1f

using bf16x8 = __attribute__((ext_vector_type(8))) short;
using f32x4  = __attribute__((ext_vector_type(4))) float;

// ---------- helpers ----------
__device__ __forceinline__ uint32_t f2bf(float f) {
  uint32_t u = __float_as_uint(f);
  return (u + 0x7fffu + ((u >> 16) & 1u)) >> 16;
}
__device__ __forceinline__ uint32_t pack2bf(float x, float y) {
  return f2bf(x) | (f2bf(y) << 16);
}

// ---------- kernel 1: normalize fp32 rows -> bf16 in MFMA-FRAGMENT layout ----
// Block = 256 thr, 16 rows. Output: one 16KB "frag-tile" per block:
//   frag-tile f covers rows [f*16, f*16+16); within it, fragment kc (1KB,
//   kc=0..15) covers k in [kc*32, kc*32+32); 16B unit u = g*16 + rs holds
//   row rs, k = kc*32 + g*8 .. +8  — exactly the 16x16x32 MFMA A/B operand
//   order, so a GEMM lane loads its fragment at base + lane*16 (coalesced).
__global__ __launch_bounds__(256)
void normalize_relayout(const float* __restrict__ src, uint16_t* __restrict__ dst) {
  __shared__ uint16_t lds[16][520];      // 1040B row stride (bank skew)
  const int lane = threadIdx.x & 63;
  const int wv = threadIdx.x >> 6;
  const size_t R0 = (size_t)blockIdx.x << 4;
  #pragma unroll
  for (int i = 0; i < 4; ++i) {
    const int r = (wv << 2) + i;         // local row 0..15
    const float4* s = (const float4*)(src + (R0 + r) * ND) + (lane << 1);
    float4 a = s[0], b = s[1];
    float ss = a.x*a.x + a.y*a.y + a.z*a.z + a.w*a.w
             + b.x*b.x + b.y*b.y + b.z*b.z + b.w*b.w;
    #pragma unroll
    for (int o = 32; o; o >>= 1) ss += __shfl_xor(ss, o);
    const float inv = 1.0f / fmaxf(sqrtf(ss), 1e-8f);
    uint4 o4;
    o4.x = pack2bf(a.x * inv, a.y * inv);
    o4.y = pack2bf(a.z * inv, a.w * inv);
    o4.z = pack2bf(b.x * inv, b.y * inv);
    o4.w = pack2bf(b.z * inv, b.w * inv);
    *(uint4*)(&lds[r][lane << 3]) = o4;  // row-major, byte off lane*16
  }
  __syncthreads();
  // transposed write: 16KB contiguous per block, fully coalesced
  uint16_t* out = dst + ((size_t)blockIdx.x << 13);
  #pragma unroll
  for (int c = 0; c < 4; ++c) {
    const int idx = (c << 8) + threadIdx.x;        // 16B-unit index 0..1023
    const int kc = idx >> 6, g = (idx >> 4) & 3, rs = idx & 15;
    uint4 v = *(const uint4*)(&lds[rs][(kc << 5) + (g << 3)]);
    ((uint4*)out)[idx] = v;
  }
}

// ---------- kernel 2: exact fp32 target cosine t_b ----------
__global__ void target_cos_kernel(const float* __restrict__ x,
                                  const float* __restrict__ cls,
                                  const int* __restrict__ tgt,
                                  float* __restrict__ t) {
  const int b = blockIdx.x;
  const int row = tgt[b];
  const float2* xr = (const float2*)(x + (size_t)b * ND);
  const float2* cr = (const float2*)(cls + (size_t)row * ND);
  float2 xv = xr[threadIdx.x], cv = cr[threadIdx.x];
  float sx = xv.x * xv.x + xv.y * xv.y;
  float sc = cv.x * cv.x + cv.y * cv.y;
  float sd = xv.x * cv.x + xv.y * cv.y;
  #pragma unroll
  for (int o = 32; o; o >>= 1) {
    sx += __shfl_down(sx, o);
    sc += __shfl_down(sc, o);
    sd += __shfl_down(sd, o);
  }
  __shared__ float r[3][4];
  const int wv = threadIdx.x >> 6;
  if ((threadIdx.x & 63) == 0) { r[0][wv] = sx; r[1][wv] = sc; r[2][wv] = sd; }
  __syncthreads();
  if (threadIdx.x == 0) {
    float ax = r[0][0] + r[0][1] + r[0][2] + r[0][3];
    float ac = r[1][0] + r[1][1] + r[1][2] + r[1][3];
    float ad = r[2][0] + r[2][1] + r[2][2] + r[2][3];
    t[b] = ad / (fmaxf(sqrtf(ax), 1e-8f) * fmaxf(sqrtf(ac), 1e-8f));
  }
}

// ---------- kernel 3: fragment-layout MFMA GEMM, no LDS, no K-loop barriers --
// 256 thr = 4 waves (2x2). Block tile 128x128, wave 64x64 = 4x4 of 16x16x32.
// 16 k-steps (BK=32). All fragment loads are base+lane*16 (1KB coalesced).
// Depth-2 register pipeline; latency hidden by 3 waves/SIMD TLP.
__global__ __launch_bounds__(256, 3)
void hinge_gemm_frag(const uint16_t* __restrict__ Wf,   // frag-layout classes
                     const uint16_t* __restrict__ Xf,   // frag-layout inputs
                     const float* __restrict__ t,       // [NB]
                     float* __restrict__ accum) {       // [64]
  const int id = blockIdx.x;
  // XCD swizzle: m-tile pinned to XCD via id&7; 8 n-tiles reuse Wf from L2
  const int nt = (id >> 3) & 7;
  const int mt = (id & 7) + ((id >> 6) << 3);
  if (mt >= MT) return;
  const int m0 = mt << 7, n0 = nt << 7;
  const int lane = threadIdx.x & 63;
  const int wv = threadIdx.x >> 6;
  const int wm = wv & 1, wn = wv >> 1;
  const int lr = lane & 15;

  // fragment pointers: frag-tile f at f*8192 elems; kc at +kc*512; lane*8 elems
  const uint16_t* pA[4];
  const uint16_t* pB[4];
  #pragma unroll
  for (int ms = 0; ms < 4; ++ms) {
    const int fA = (m0 >> 4) + (wm << 2) + ms;   // may overrun Wf for mt=781:
    pA[ms] = Wf + (size_t)fA * 8192 + (lane << 3); // stays inside ws, masked below
  }
  #pragma unroll
  for (int j = 0; j < 4; ++j) {
    const int fB = (n0 >> 4) + (wn << 2) + j;
    pB[j] = Xf + (size_t)fB * 8192 + (lane << 3);
  }

  f32x4 acc[4][4];
  #pragma unroll
  for (int i = 0; i < 4; ++i)
    #pragma unroll
    for (int j = 0; j < 4; ++j)
      acc[i][j] = (f32x4){0.f, 0.f, 0.f, 0.f};

  bf16x8 ab[2][4], bb[2][4];
  #pragma unroll
  for (int ms = 0; ms < 4; ++ms) ab[0][ms] = *(const bf16x8*)(pA[ms]);
  #pragma unroll
  for (int j = 0; j < 4; ++j)    bb[0][j]  = *(const bf16x8*)(pB[j]);

  #pragma unroll
  for (int kk = 0; kk < 16; ++kk) {
    const int cur = kk & 1, nxt = cur ^ 1;
    if (kk < 15) {
      #pragma unroll
      for (int ms = 0; ms < 4; ++ms)
        ab[nxt][ms] = *(const bf16x8*)(pA[ms] + ((kk + 1) << 9));
      #pragma unroll
      for (int j = 0; j < 4; ++j)
        bb[nxt][j] = *(const bf16x8*)(pB[j] + ((kk + 1) << 9));
    }
    #pragma unroll
    for (int ms = 0; ms < 4; ++ms)
      #pragma unroll
      for (int j = 0; j < 4; ++j)
        acc[ms][j] = __builtin_amdgcn_mfma_f32_16x16x32_bf16(ab[cur][ms], bb[cur][j], acc[ms][j], 0, 0, 0);
  }

  // ---- epilogue: hinge + block reduction ----
  // C/D: col(N) = lane&15, row(M) = (lane>>4)*4 + reg
  float local = 0.f;
  const int rb4 = (lane >> 4) << 2;
  #pragma unroll
  for (int j = 0; j < 4; ++j) {
    const int n = n0 + (wn << 6) + (j << 4) + lr;
    const float base = MARGINF - t[n];
    #pragma unroll
    for (int ms = 0; ms < 4; ++ms) {
      const int mr = m0 + (wm << 6) + (ms << 4) + rb4;
      f32x4 v = acc[ms][j];
      #pragma unroll
      for (int rr = 0; rr < 4; ++rr)
        if (mr + rr < NC) local += fmaxf(base + v[rr], 0.f);
    }
  }
  #pragma unroll
  for (int o = 32; o; o >>= 1) local += __shfl_down(local, o);
  __shared__ float part[4];
  if (lane == 0) part[wv] = local;
  __syncthreads();
  if (threadIdx.x == 0)
    atomicAdd(&accum[id & 63], part[0] + part[1] + part[2] + part[3]);
}

// ---------- kernel 4: finalize ----------
__global__ void finalize_kernel(const float* __restrict__ accum, float* __restrict__ out) {
  float s = 0.f;
  #pragma unroll
  for (int i = 0; i < 64; ++i) s += accum[i];
  out[0] = s * (1.0f / (float)NB) - MARGINF;
}

// ---------- workspace layout ----------
//   Wf   : 0            .. 102,400,000   (6250 frag-tiles x 16KB)
//   Xf   : 102,400,000  .. 103,448,576   (64 frag-tiles x 16KB)
//   t    : 103,448,576  .. 103,452,672   (NB fp32)
//   acc  : 103,452,672  .. +256          (64 fp32)
#define WS_WF 0
#define WS_XF 102400000ull
#define WS_T  103448576ull
#define WS_ACC 103452672ull

extern "C" void kernel_launch(void* const* d_in, const int* in_sizes, int n_in,
                              void* d_out, int out_size, void* d_ws, size_t ws_size,
                              hipStream_t stream) {
  const float* inputs = (const float*)d_in[0];
  const float* cls    = (const float*)d_in[1];
  const int*   tgt    = (const int*)d_in[2];
  float* out = (float*)d_out;
  char* ws = (char*)d_ws;
  uint16_t* Wf = (uint16_t*)(ws + WS_WF);
  uint16_t* Xf = (uint16_t*)(ws + WS_XF);
  float* t     = (float*)(ws + WS_T);
  float* accum = (float*)(ws + WS_ACC);

  (void)hipMemsetAsync(accum, 0, 64 * sizeof(float), stream);
  normalize_relayout<<<64, 256, 0, stream>>>(inputs, Xf);     // 1024 rows
  normalize_relayout<<<6250, 256, 0, stream>>>(cls, Wf);      // 100000 rows
  target_cos_kernel<<<NB, 256, 0, stream>>>(inputs, cls, tgt, t);
  // 98 groups x (8 m-tiles x 8 n-tiles) = 6272 blocks, mt guarded at 782
  hinge_gemm_frag<<<6272, 256, 0, stream>>>(Wf, Xf, t, accum);
  finalize_kernel<<<1, 1, 0, stream>>>(accum, out);
}